// Round 14
// baseline (166.609 us; speedup 1.0000x reference)
//
#include <hip/hip_runtime.h>

// ---------------------------------------------------------------------------
// MultiHeadSelfAttentionWithRoPE: B=4, S=2048, D_MODEL=1024, H=16, D_K=64
// fused cvt | 3-buf counted-vmcnt 256x128 QKV GEMM (RoPE fused; V transposed;
// A-panel XCD-pinned) | 8-warp x 64-q flash attn (K/V-frag reuse, permlane
// pack, fixed-base softmax) | 3-buf out GEMM
// ---------------------------------------------------------------------------

typedef float f32x4 __attribute__((ext_vector_type(4)));
typedef float f32x16 __attribute__((ext_vector_type(16)));
typedef __bf16 bf16x8 __attribute__((ext_vector_type(8)));
typedef __bf16 bf16x4 __attribute__((ext_vector_type(4)));
typedef unsigned int u32;

#define MFMA16(a, b, c) __builtin_amdgcn_mfma_f32_16x16x32_bf16((a), (b), (c), 0, 0, 0)
#define MFMA32(a, b, c) __builtin_amdgcn_mfma_f32_32x32x16_bf16((a), (b), (c), 0, 0, 0)

#define GL16(gp, lp)                                                        \
  __builtin_amdgcn_global_load_lds(                                         \
      (const __attribute__((address_space(1))) void*)(gp),                  \
      (__attribute__((address_space(3))) void*)(lp), 16, 0, 0)

#define EXP2(x) __builtin_amdgcn_exp2f(x)
#define QSCALE 0.18033688011112042f

// ---------------- fused cvt: x (f32->bf16), 4 weights, RoPE table ----------
__global__ void cvt_all(const float* __restrict__ x,
                        const float* __restrict__ wq, const float* __restrict__ wk,
                        const float* __restrict__ wv, const float* __restrict__ wo,
                        __bf16* __restrict__ xb, __bf16* __restrict__ wdst,
                        float* __restrict__ ct, float* __restrict__ st) {
  const int bid = blockIdx.x;
  if (bid < 8192) {
    int i = bid * 256 + threadIdx.x;
    float4 v = ((const float4*)x)[i];
    bf16x4 o;
    o[0] = (__bf16)v.x; o[1] = (__bf16)v.y; o[2] = (__bf16)v.z; o[3] = (__bf16)v.w;
    ((bf16x4*)xb)[i] = o;
  } else if (bid < 12288) {
    int i = (bid - 8192) * 256 + threadIdx.x;
    int sel = i >> 18;
    const float* src = sel == 0 ? wq : sel == 1 ? wk : sel == 2 ? wv : wo;
    int j = i & 262143;
    float4 v = ((const float4*)src)[j];
    bf16x4 o;
    o[0] = (__bf16)v.x; o[1] = (__bf16)v.y; o[2] = (__bf16)v.z; o[3] = (__bf16)v.w;
    ((bf16x4*)wdst)[i] = o;
  } else {
    int i = (bid - 12288) * 256 + threadIdx.x;  // 65536 = 2048*32
    int pos = i >> 5, f = i & 31;
    float inv = powf(10000.0f, -(float)f * (1.0f / 32.0f));
    float a = (float)pos * inv;
    ct[i] = cosf(a);
    st[i] = sinf(a);
  }
}

// --------- 3-buf counted-vmcnt GEMM: C = A(8192xK) * B(NxK)^T --------------
template <int MODE>
__global__ __launch_bounds__(512, 2) void gemm8(const __bf16* __restrict__ A,
                                                const __bf16* __restrict__ Bw,
                                                void* __restrict__ Cout,
                                                const int* __restrict__ tpos,
                                                const float* __restrict__ ct,
                                                const float* __restrict__ st) {
  __shared__ __align__(16) char LB[147456];  // A 3x32KB | B 3x16KB
  const int nk = 16;  // K=1024 / BK=64
  const int t = threadIdx.x, w = t >> 6, l = t & 63;
  const int lr = l & 15, lg = l >> 4;
  const int wr = w >> 1, wc = w & 1;
  const int id = blockIdx.x;
  const int xcd = id & 7, i = id >> 3;
  const int bm = xcd * 4 + (i & 3);  // 4 panels per XCD, L2-resident
  const int bn = i >> 2;             // sweeps 0..23 (MODE4) / 0..7 (MODE3)

  const int srow = t >> 3;
  const int scbs = ((t & 7) * 16) ^ ((srow & 7) << 4);
  const char* Ag = (const char*)A + (size_t)(bm * 256 + srow) * 2048 + scbs;
  const char* Bg = (const char*)Bw + (size_t)(bn * 128 + srow) * 2048 + scbs;
  char* lw = LB + w * 1024;  // wave-uniform dest base

#define STAGE_AB(d, KT)                                                    \
  {                                                                        \
    GL16(Ag + (KT) * 128, lw + (d) * 32768);                               \
    GL16(Ag + (KT) * 128 + (size_t)64 * 2048, lw + (d) * 32768 + 8192);    \
    GL16(Ag + (KT) * 128 + (size_t)128 * 2048, lw + (d) * 32768 + 16384);  \
    GL16(Ag + (KT) * 128 + (size_t)192 * 2048, lw + (d) * 32768 + 24576);  \
    GL16(Bg + (KT) * 128, lw + 98304 + (d) * 16384);                       \
    GL16(Bg + (KT) * 128 + (size_t)64 * 2048, lw + 98304 + (d) * 16384 + 8192); \
  }

  const int sw = (lr & 7) << 4;
  const int c0 = (lg * 16) ^ sw;       // kk=0
  const int c1 = (64 + lg * 16) ^ sw;  // kk=1

  f32x4 acc[4][4] = {};

  STAGE_AB(0, 0)
  STAGE_AB(1, 1)
  asm volatile("s_waitcnt vmcnt(6)" ::: "memory");
  __builtin_amdgcn_s_barrier();
  __builtin_amdgcn_sched_barrier(0);

  for (int kt = 0; kt < nk; ++kt) {
    const int X = kt % 3;
    if (kt + 2 < nk) STAGE_AB((kt + 2) % 3, kt + 2)
    const char* Ab = LB + X * 32768;
    const char* Bb = LB + 98304 + X * 16384;
    bf16x8 af[4][2], bf[4][2];
#pragma unroll
    for (int m = 0; m < 4; ++m) {
      const int ar = (wr * 64 + m * 16 + lr) * 128;
      af[m][0] = *(const bf16x8*)(Ab + ar + c0);
      af[m][1] = *(const bf16x8*)(Ab + ar + c1);
    }
#pragma unroll
    for (int n = 0; n < 4; ++n) {
      const int br = (wc * 64 + n * 16 + lr) * 128;
      bf[n][0] = *(const bf16x8*)(Bb + br + c0);
      bf[n][1] = *(const bf16x8*)(Bb + br + c1);
    }
    __builtin_amdgcn_s_setprio(1);
#pragma unroll
    for (int m = 0; m < 4; ++m)
#pragma unroll
      for (int n = 0; n < 4; ++n)
#pragma unroll
        for (int kk = 0; kk < 2; ++kk)
          acc[m][n] = MFMA16(af[m][kk], bf[n][kk], acc[m][n]);
    __builtin_amdgcn_s_setprio(0);
    if (kt + 2 < nk) {
      asm volatile("s_waitcnt vmcnt(6)" ::: "memory");
      __builtin_amdgcn_s_barrier();
      __builtin_amdgcn_sched_barrier(0);
    } else if (kt + 1 < nk) {
      asm volatile("s_waitcnt vmcnt(0)" ::: "memory");
      __builtin_amdgcn_s_barrier();
      __builtin_amdgcn_sched_barrier(0);
    }
  }

  // ---------------- epilogue ----------------
  if (MODE == 3) {
    float* outp = (float*)Cout;
#pragma unroll
    for (int m = 0; m < 4; ++m)
#pragma unroll
      for (int n = 0; n < 4; ++n)
#pragma unroll
        for (int e = 0; e < 4; ++e) {
          const int grow = bm * 256 + wr * 64 + m * 16 + lg * 4 + e;
          const int gcol = bn * 128 + wc * 64 + n * 16 + lr;
          outp[(size_t)grow * 1024 + gcol] = acc[m][n][e];
        }
  } else {
    const int seg = bn >> 3;  // 0=Q 1=K 2=V
    const int bnn = bn & 7;
    if (seg < 2) {
      const int h = bnn * 2 + wc;
      __bf16* base = (__bf16*)Cout + (size_t)seg * 8388608;
#pragma unroll
      for (int m = 0; m < 4; ++m)
#pragma unroll
        for (int e = 0; e < 4; ++e) {
          const int grow = bm * 256 + wr * 64 + m * 16 + lg * 4 + e;
          const int pos = tpos[grow];
          const int b = grow >> 11, s = grow & 2047;
          __bf16* orow = &base[(((size_t)(b * 16 + h)) * 2048 + s) * 64];
#pragma unroll
          for (int j = 0; j < 2; ++j) {
            const int dd = j * 16 + lr;
            const float c = ct[pos * 32 + dd], sn = st[pos * 32 + dd];
            float x1 = acc[m][j][e], x2 = acc[m][j + 2][e];
            float o1 = x1 * c - x2 * sn;
            float o2 = x2 * c + x1 * sn;
            if (seg == 0) { o1 *= QSCALE; o2 *= QSCALE; }
            orow[dd] = (__bf16)o1;
            orow[dd + 32] = (__bf16)o2;
          }
        }
    } else {
      __bf16* base = (__bf16*)Cout + 16777216;
#pragma unroll
      for (int m = 0; m < 4; ++m)
#pragma unroll
        for (int n = 0; n < 4; ++n) {
          const int grow0 = bm * 256 + wr * 64 + m * 16 + lg * 4;
          const int gcs = bnn * 128 + wc * 64 + n * 16 + lr;
          const int b = grow0 >> 11, s = grow0 & 2047;
          const int h = gcs >> 6, d = gcs & 63;
          bf16x4 vv;
#pragma unroll
          for (int e = 0; e < 4; ++e) vv[e] = (__bf16)acc[m][n][e];
          *(bf16x4*)&base[(((size_t)(b * 16 + h)) * 64 + d) * 2048 + s] = vv;
        }
    }
  }
}

// ------------------------- paired-causal flash attention -------------------
// 256 blocks x 512 thr (8 warps x 64 q rows, two Q fragment-sets per warp).
// Each K/V ds_read_b128 feeds TWO MFMAs (one per q-set) -> LDS reads halved.
// P-pack via v_permlane32_swap_b32 (VALU, no LDS shuffles). Fixed-base softmax.
static __device__ __forceinline__ u32 pk2(float a, float b) {
  union { __bf16 h[2]; u32 w; } u;
  u.h[0] = (__bf16)a; u.h[1] = (__bf16)b;
  return u.w;
}

// w[0]={c01.lo,c45.lo} w[2]={c01.hi,c45.hi} etc. via register half-swaps
#define PACK_FRAG(SRC, OFF, OUT)                                            \
  {                                                                         \
    u32 c01 = pk2(SRC[(OFF) + 0], SRC[(OFF) + 1]);                          \
    u32 c23 = pk2(SRC[(OFF) + 2], SRC[(OFF) + 3]);                          \
    u32 c45 = pk2(SRC[(OFF) + 4], SRC[(OFF) + 5]);                          \
    u32 c67 = pk2(SRC[(OFF) + 6], SRC[(OFF) + 7]);                          \
    asm volatile("v_permlane32_swap_b32 %0, %1" : "+v"(c01), "+v"(c45));    \
    asm volatile("v_permlane32_swap_b32 %0, %1" : "+v"(c23), "+v"(c67));    \
    union { u32 w[4]; bf16x8 v; } fu_;                                      \
    fu_.w[0] = c01; fu_.w[1] = c23; fu_.w[2] = c45; fu_.w[3] = c67;         \
    OUT = fu_.v;                                                            \
  }

#define KOFF(row, cb) ((row) * 128 + ((cb) ^ (((row) & 7) << 4)))
#define VOFF(row, cb) ((row) * 256 + ((cb) ^ (((row) & 15) << 4)))

__global__ __launch_bounds__(512) void attn_fwd(const __bf16* __restrict__ Q,
                                                const __bf16* __restrict__ Kb,
                                                const __bf16* __restrict__ VTg,
                                                __bf16* __restrict__ O) {
  __shared__ __align__(16) __bf16 Ks[2][128 * 64];  // 16KB per buf
  __shared__ __align__(16) __bf16 Vs[2][64 * 128];  // 16KB per buf
  const int t = threadIdx.x, w = t >> 6, l = t & 63;
  const int lq = l & 31, hi = l >> 5;
  const int id = blockIdx.x;
  const int bh = (id & 7) + 8 * (id >> 5);  // same-head blocks share an XCD
  const int p = (id >> 3) & 3;
  const int member = w >> 2;                 // 0 = light, 1 = heavy
  const int ridx = w & 3;
  const int qb = member ? 7 - p : p;
  const int q0w = qb * 256 + ridx * 64;
  const int qrow0 = q0w + lq, qrow1 = q0w + 32 + lq;
  const size_t kbaseB = (size_t)bh * (2048 * 64 * 2);
  const size_t vbaseB = (size_t)bh * (64 * 2048 * 2);

  // staging: 512 thr x 2x16B per tile
  const int srow = t >> 3;                               // 0..63 (K rows)
  const int scolb = ((t & 7) * 16) ^ ((srow & 7) << 4);  // inverse swizzle
  const int vrow = t >> 4;                               // 0..31 (V^T rows)
  const int vcolb = ((t & 15) * 16) ^ ((vrow & 15) << 4);
  const char* kgp = (const char*)Kb + kbaseB + (size_t)srow * 128 + scolb;
  const char* vgp = (const char*)VTg + vbaseB + (size_t)vrow * 4096 + vcolb;
  char* kl = (char*)&Ks[0][0] + w * 1024;  // wave-uniform dest
  char* vl = (char*)&Vs[0][0] + w * 1024;

#define STAGE(bi, KT)                                                      \
  {                                                                        \
    GL16(kgp + (size_t)(KT) * 16384, kl + (bi) * 16384);                   \
    GL16(kgp + (size_t)(KT) * 16384 + 8192, kl + (bi) * 16384 + 8192);     \
    GL16(vgp + (size_t)(KT) * 256, vl + (bi) * 16384);                     \
    GL16(vgp + (size_t)(KT) * 256 + (size_t)32 * 4096,                     \
         vl + (bi) * 16384 + 8192);                                        \
  }

  // Q fragments for both q-sets (RoPE + 0.125*log2e folded in by GEMM)
  const size_t qbase = (size_t)bh * (2048 * 64);
  bf16x8 qf0[4], qf1[4];
#pragma unroll
  for (int ds = 0; ds < 4; ++ds) {
    qf0[ds] = *(const bf16x8*)&Q[qbase + (size_t)qrow0 * 64 + ds * 16 + hi * 8];
    qf1[ds] = *(const bf16x8*)&Q[qbase + (size_t)qrow1 * 64 + ds * 16 + hi * 8];
  }

  f32x16 o00 = {}, o01 = {}, o10 = {}, o11 = {};
  float lsum0 = 0.0f, lsum1 = 0.0f;

  const int nkt = 2 * (7 - p) + 2;  // block-uniform (heavy member bound)
  STAGE(0, 0)
  asm volatile("s_waitcnt vmcnt(0)" ::: "memory");
  __builtin_amdgcn_s_barrier();
  __builtin_amdgcn_sched_barrier(0);
  int cur = 0;
  for (int kt = 0; kt < nkt; ++kt) {
    if (kt + 1 < nkt) STAGE(cur ^ 1, kt + 1)
    const char* kc = (const char*)&Ks[cur][0];
    const char* vc = (const char*)&Vs[cur][0];

#pragma unroll
    for (int sub = 0; sub < 2; ++sub) {
      const int k0 = kt * 128 + sub * 64;
      if (k0 <= q0w + 63) {  // warp-uniform causal skip
        const char* kcs = kc + sub * 8192;
        f32x16 s00 = {}, s01 = {}, s10 = {}, s11 = {};
        __builtin_amdgcn_s_setprio(1);
#pragma unroll
        for (int ds = 0; ds < 4; ++ds) {
          bf16x8 kf = *(const bf16x8*)(kcs + KOFF(lq, ds * 32 + hi * 16));
          s00 = MFMA32(kf, qf0[ds], s00);
          s01 = MFMA32(kf, qf1[ds], s01);
        }
#pragma unroll
        for (int ds = 0; ds < 4; ++ds) {
          bf16x8 kf = *(const bf16x8*)(kcs + KOFF(32 + lq, ds * 32 + hi * 16));
          s10 = MFMA32(kf, qf0[ds], s10);
          s11 = MFMA32(kf, qf1[ds], s11);
        }
        __builtin_amdgcn_s_setprio(0);

        if (k0 + 63 > q0w) {  // causal mask (edge tiles only)
#pragma unroll
          for (int r = 0; r < 16; ++r) {
            const int kl_ = k0 + (r & 3) + 8 * (r >> 2) + 4 * hi;
            s00[r] = (kl_ > qrow0) ? -1e30f : s00[r];
            s01[r] = (kl_ > qrow1) ? -1e30f : s01[r];
            s10[r] = (kl_ + 32 > qrow0) ? -1e30f : s10[r];
            s11[r] = (kl_ + 32 > qrow1) ? -1e30f : s11[r];
          }
        }

        // fixed-base exp2 + per-set row sums
        {
          float ra = 0.f, rb = 0.f, rc = 0.f, rd = 0.f;
#pragma unroll
          for (int r = 0; r < 16; ++r) {
            float e0 = EXP2(s00[r]);
            float e1 = EXP2(s10[r]);
            s00[r] = e0; s10[r] = e1;
            if (r & 1) { rb += e0; rd += e1; } else { ra += e0; rc += e1; }
          }
          float rs = (ra + rb) + (rc + rd);
          rs += __shfl_xor(rs, 32);
          lsum0 += rs;
        }
        {
          float ra = 0.f, rb = 0.f, rc = 0.f, rd = 0.f;
#pragma unroll
          for (int r = 0; r < 16; ++r) {
            float e0 = EXP2(s01[r]);
            float e1 = EXP2(s11[r]);
            s01[r] = e0; s11[r] = e1;
            if (r & 1) { rb += e0; rd += e1; } else { ra += e0; rc += e1; }
          }
          float rs = (ra + rb) + (rc + rd);
          rs += __shfl_xor(rs, 32);
          lsum1 += rs;
        }

        bf16x8 pa0[4], pa1[4];
        PACK_FRAG(s00, 0, pa0[0])
        PACK_FRAG(s00, 8, pa0[1])
        PACK_FRAG(s10, 0, pa0[2])
        PACK_FRAG(s10, 8, pa0[3])
        PACK_FRAG(s01, 0, pa1[0])
        PACK_FRAG(s01, 8, pa1[1])
        PACK_FRAG(s11, 0, pa1[2])
        PACK_FRAG(s11, 8, pa1[3])

        const int vcb0 = sub * 128;
        __builtin_amdgcn_s_setprio(1);
#pragma unroll
        for (int fi = 0; fi < 4; ++fi) {
          bf16x8 vf = *(const bf16x8*)(vc + VOFF(lq, vcb0 + fi * 32 + hi * 16));
          o00 = MFMA32(vf, pa0[fi], o00);
          o10 = MFMA32(vf, pa1[fi], o10);
        }
#pragma unroll
        for (int fi = 0; fi < 4; ++fi) {
          bf16x8 vf = *(const bf16x8*)(vc + VOFF(32 + lq, vcb0 + fi * 32 + hi * 16));
          o01 = MFMA32(vf, pa0[fi], o01);
          o11 = MFMA32(vf, pa1[fi], o11);
        }
        __builtin_amdgcn_s_setprio(0);
      }
    }
    asm volatile("s_waitcnt vmcnt(0)" ::: "memory");
    __builtin_amdgcn_s_barrier();
    __builtin_amdgcn_sched_barrier(0);
    cur ^= 1;
  }

  // epilogue: O^T reg r -> d = half*32 + (r&3) + 8*(r>>2) + 4*hi, q = lane&31
  const int b = bh >> 4, h = bh & 15;
  {
    float inv = 1.0f / lsum0;
    __bf16* orow = O + ((size_t)(b * 2048 + qrow0)) * 1024 + h * 64;
#pragma unroll
    for (int rq = 0; rq < 4; ++rq) {
      bf16x4 v0, v1;
#pragma unroll
      for (int e = 0; e < 4; ++e) {
        v0[e] = (__bf16)(o00[rq * 4 + e] * inv);
        v1[e] = (__bf16)(o01[rq * 4 + e] * inv);
      }
      *(bf16x4*)&orow[8 * rq + 4 * hi] = v0;
      *(bf16x4*)&orow[32 + 8 * rq + 4 * hi] = v1;
    }
  }
  {
    float inv = 1.0f / lsum1;
    __bf16* orow = O + ((size_t)(b * 2048 + qrow1)) * 1024 + h * 64;
#pragma unroll
    for (int rq = 0; rq < 4; ++rq) {
      bf16x4 v0, v1;
#pragma unroll
      for (int e = 0; e < 4; ++e) {
        v0[e] = (__bf16)(o10[rq * 4 + e] * inv);
        v1[e] = (__bf16)(o11[rq * 4 + e] * inv);
      }
      *(bf16x4*)&orow[8 * rq + 4 * hi] = v0;
      *(bf16x4*)&orow[32 + 8 * rq + 4 * hi] = v1;
    }
  }
}

// ---------------------------------------------------------------------------
extern "C" void kernel_launch(void* const* d_in, const int* in_sizes, int n_in,
                              void* d_out, int out_size, void* d_ws, size_t ws_size,
                              hipStream_t stream) {
  const float* x = (const float*)d_in[0];
  const float* wq = (const float*)d_in[1];
  const float* wk = (const float*)d_in[2];
  const float* wv = (const float*)d_in[3];
  const float* wo = (const float*)d_in[4];
  const int* tpos = (const int*)d_in[5];
  float* out = (float*)d_out;

  const size_t SZ_X = 8192u * 1024u * 2u;
  const size_t SZ_W = 1024u * 1024u * 2u;
  const size_t SZ_T = 2048u * 32u * 4u;
  const size_t NEED = SZ_X * 4 + SZ_W * 4 + SZ_T * 2;
  if (ws_size < NEED) return;

  char* p = (char*)d_ws;
  __bf16* xb  = (__bf16*)p; p += SZ_X;   // reused as attention output (AO)
  __bf16* wqb = (__bf16*)p; p += SZ_W;   // 4 weights contiguous (wq|wk|wv|wo)
  __bf16* wkb = (__bf16*)p; p += SZ_W;
  __bf16* wvb = (__bf16*)p; p += SZ_W;
  __bf16* wob = (__bf16*)p; p += SZ_W;
  __bf16* Qb  = (__bf16*)p; p += SZ_X;   // Q | K | V^T contiguous
  __bf16* Kbf = (__bf16*)p; p += SZ_X;
  __bf16* VTg = (__bf16*)p; p += SZ_X;
  float* ct = (float*)p; p += SZ_T;
  float* st = (float*)p; p += SZ_T;
  __bf16* AOb = xb;
  (void)wkb; (void)wvb;

  cvt_all<<<12544, 256, 0, stream>>>(x, wq, wk, wv, wo, xb, wqb, ct, st);

  // fused QKV: B = wq|wk|wv rows (contiguous), N=3072; grid 768 = 3/CU
  gemm8<4><<<768, 512, 0, stream>>>(xb, wqb, (void*)Qb, tpos, ct, st);

  attn_fwd<<<256, 512, 0, stream>>>(Qb, Kbf, VTg, AOb);

  // out projection: N=1024; grid 256 = 1/CU
  gemm8<3><<<256, 512, 0, stream>>>(AOb, wob, (void*)out, tpos, ct, st);
}

// Round 15
// 161.530 us; speedup vs baseline: 1.0314x; 1.0314x over previous
//
#include <hip/hip_runtime.h>

// ---------------------------------------------------------------------------
// MultiHeadSelfAttentionWithRoPE: B=4, S=2048, D_MODEL=1024, H=16, D_K=64
// fused cvt | 3-buf counted-vmcnt 256x128 QKV GEMM (RoPE fused; V transposed;
// A-panel XCD-pinned) | 16-warp paired-causal flash attn (fixed-base softmax,
// permlane P-pack) | 3-buf out GEMM
// ---------------------------------------------------------------------------

typedef float f32x4 __attribute__((ext_vector_type(4)));
typedef float f32x16 __attribute__((ext_vector_type(16)));
typedef __bf16 bf16x8 __attribute__((ext_vector_type(8)));
typedef __bf16 bf16x4 __attribute__((ext_vector_type(4)));
typedef unsigned int u32;

#define MFMA16(a, b, c) __builtin_amdgcn_mfma_f32_16x16x32_bf16((a), (b), (c), 0, 0, 0)
#define MFMA32(a, b, c) __builtin_amdgcn_mfma_f32_32x32x16_bf16((a), (b), (c), 0, 0, 0)

#define GL16(gp, lp)                                                        \
  __builtin_amdgcn_global_load_lds(                                         \
      (const __attribute__((address_space(1))) void*)(gp),                  \
      (__attribute__((address_space(3))) void*)(lp), 16, 0, 0)

#define EXP2(x) __builtin_amdgcn_exp2f(x)
#define QSCALE 0.18033688011112042f

// ---------------- fused cvt: x (f32->bf16), 4 weights, RoPE table ----------
__global__ void cvt_all(const float* __restrict__ x,
                        const float* __restrict__ wq, const float* __restrict__ wk,
                        const float* __restrict__ wv, const float* __restrict__ wo,
                        __bf16* __restrict__ xb, __bf16* __restrict__ wdst,
                        float* __restrict__ ct, float* __restrict__ st) {
  const int bid = blockIdx.x;
  if (bid < 8192) {
    int i = bid * 256 + threadIdx.x;
    float4 v = ((const float4*)x)[i];
    bf16x4 o;
    o[0] = (__bf16)v.x; o[1] = (__bf16)v.y; o[2] = (__bf16)v.z; o[3] = (__bf16)v.w;
    ((bf16x4*)xb)[i] = o;
  } else if (bid < 12288) {
    int i = (bid - 8192) * 256 + threadIdx.x;
    int sel = i >> 18;
    const float* src = sel == 0 ? wq : sel == 1 ? wk : sel == 2 ? wv : wo;
    int j = i & 262143;
    float4 v = ((const float4*)src)[j];
    bf16x4 o;
    o[0] = (__bf16)v.x; o[1] = (__bf16)v.y; o[2] = (__bf16)v.z; o[3] = (__bf16)v.w;
    ((bf16x4*)wdst)[i] = o;
  } else {
    int i = (bid - 12288) * 256 + threadIdx.x;  // 65536 = 2048*32
    int pos = i >> 5, f = i & 31;
    float inv = powf(10000.0f, -(float)f * (1.0f / 32.0f));
    float a = (float)pos * inv;
    ct[i] = cosf(a);
    st[i] = sinf(a);
  }
}

// --------- 3-buf counted-vmcnt GEMM: C = A(8192xK) * B(NxK)^T --------------
template <int MODE>
__global__ __launch_bounds__(512, 2) void gemm8(const __bf16* __restrict__ A,
                                                const __bf16* __restrict__ Bw,
                                                void* __restrict__ Cout,
                                                const int* __restrict__ tpos,
                                                const float* __restrict__ ct,
                                                const float* __restrict__ st) {
  __shared__ __align__(16) char LB[147456];  // A 3x32KB | B 3x16KB
  const int nk = 16;  // K=1024 / BK=64
  const int t = threadIdx.x, w = t >> 6, l = t & 63;
  const int lr = l & 15, lg = l >> 4;
  const int wr = w >> 1, wc = w & 1;
  const int id = blockIdx.x;
  const int xcd = id & 7, i = id >> 3;
  const int bm = xcd * 4 + (i & 3);  // 4 panels per XCD, L2-resident
  const int bn = i >> 2;             // sweeps 0..23 (MODE4) / 0..7 (MODE3)

  const int srow = t >> 3;
  const int scbs = ((t & 7) * 16) ^ ((srow & 7) << 4);
  const char* Ag = (const char*)A + (size_t)(bm * 256 + srow) * 2048 + scbs;
  const char* Bg = (const char*)Bw + (size_t)(bn * 128 + srow) * 2048 + scbs;
  char* lw = LB + w * 1024;  // wave-uniform dest base

#define STAGE_AB(d, KT)                                                    \
  {                                                                        \
    GL16(Ag + (KT) * 128, lw + (d) * 32768);                               \
    GL16(Ag + (KT) * 128 + (size_t)64 * 2048, lw + (d) * 32768 + 8192);    \
    GL16(Ag + (KT) * 128 + (size_t)128 * 2048, lw + (d) * 32768 + 16384);  \
    GL16(Ag + (KT) * 128 + (size_t)192 * 2048, lw + (d) * 32768 + 24576);  \
    GL16(Bg + (KT) * 128, lw + 98304 + (d) * 16384);                       \
    GL16(Bg + (KT) * 128 + (size_t)64 * 2048, lw + 98304 + (d) * 16384 + 8192); \
  }

  const int sw = (lr & 7) << 4;
  const int c0 = (lg * 16) ^ sw;       // kk=0
  const int c1 = (64 + lg * 16) ^ sw;  // kk=1

  f32x4 acc[4][4] = {};

  STAGE_AB(0, 0)
  STAGE_AB(1, 1)
  asm volatile("s_waitcnt vmcnt(6)" ::: "memory");
  __builtin_amdgcn_s_barrier();
  __builtin_amdgcn_sched_barrier(0);

  for (int kt = 0; kt < nk; ++kt) {
    const int X = kt % 3;
    if (kt + 2 < nk) STAGE_AB((kt + 2) % 3, kt + 2)
    const char* Ab = LB + X * 32768;
    const char* Bb = LB + 98304 + X * 16384;
    bf16x8 af[4][2], bf[4][2];
#pragma unroll
    for (int m = 0; m < 4; ++m) {
      const int ar = (wr * 64 + m * 16 + lr) * 128;
      af[m][0] = *(const bf16x8*)(Ab + ar + c0);
      af[m][1] = *(const bf16x8*)(Ab + ar + c1);
    }
#pragma unroll
    for (int n = 0; n < 4; ++n) {
      const int br = (wc * 64 + n * 16 + lr) * 128;
      bf[n][0] = *(const bf16x8*)(Bb + br + c0);
      bf[n][1] = *(const bf16x8*)(Bb + br + c1);
    }
    __builtin_amdgcn_s_setprio(1);
#pragma unroll
    for (int m = 0; m < 4; ++m)
#pragma unroll
      for (int n = 0; n < 4; ++n)
#pragma unroll
        for (int kk = 0; kk < 2; ++kk)
          acc[m][n] = MFMA16(af[m][kk], bf[n][kk], acc[m][n]);
    __builtin_amdgcn_s_setprio(0);
    if (kt + 2 < nk) {
      asm volatile("s_waitcnt vmcnt(6)" ::: "memory");
      __builtin_amdgcn_s_barrier();
      __builtin_amdgcn_sched_barrier(0);
    } else if (kt + 1 < nk) {
      asm volatile("s_waitcnt vmcnt(0)" ::: "memory");
      __builtin_amdgcn_s_barrier();
      __builtin_amdgcn_sched_barrier(0);
    }
  }

  // ---------------- epilogue ----------------
  if (MODE == 3) {
    float* outp = (float*)Cout;
#pragma unroll
    for (int m = 0; m < 4; ++m)
#pragma unroll
      for (int n = 0; n < 4; ++n)
#pragma unroll
        for (int e = 0; e < 4; ++e) {
          const int grow = bm * 256 + wr * 64 + m * 16 + lg * 4 + e;
          const int gcol = bn * 128 + wc * 64 + n * 16 + lr;
          outp[(size_t)grow * 1024 + gcol] = acc[m][n][e];
        }
  } else {
    const int seg = bn >> 3;  // 0=Q 1=K 2=V
    const int bnn = bn & 7;
    if (seg < 2) {
      const int h = bnn * 2 + wc;
      __bf16* base = (__bf16*)Cout + (size_t)seg * 8388608;
#pragma unroll
      for (int m = 0; m < 4; ++m)
#pragma unroll
        for (int e = 0; e < 4; ++e) {
          const int grow = bm * 256 + wr * 64 + m * 16 + lg * 4 + e;
          const int pos = tpos[grow];
          const int b = grow >> 11, s = grow & 2047;
          __bf16* orow = &base[(((size_t)(b * 16 + h)) * 2048 + s) * 64];
#pragma unroll
          for (int j = 0; j < 2; ++j) {
            const int dd = j * 16 + lr;
            const float c = ct[pos * 32 + dd], sn = st[pos * 32 + dd];
            float x1 = acc[m][j][e], x2 = acc[m][j + 2][e];
            float o1 = x1 * c - x2 * sn;
            float o2 = x2 * c + x1 * sn;
            if (seg == 0) { o1 *= QSCALE; o2 *= QSCALE; }
            orow[dd] = (__bf16)o1;
            orow[dd + 32] = (__bf16)o2;
          }
        }
    } else {
      __bf16* base = (__bf16*)Cout + 16777216;
#pragma unroll
      for (int m = 0; m < 4; ++m)
#pragma unroll
        for (int n = 0; n < 4; ++n) {
          const int grow0 = bm * 256 + wr * 64 + m * 16 + lg * 4;
          const int gcs = bnn * 128 + wc * 64 + n * 16 + lr;
          const int b = grow0 >> 11, s = grow0 & 2047;
          const int h = gcs >> 6, d = gcs & 63;
          bf16x4 vv;
#pragma unroll
          for (int e = 0; e < 4; ++e) vv[e] = (__bf16)acc[m][n][e];
          *(bf16x4*)&base[(((size_t)(b * 16 + h)) * 64 + d) * 2048 + s] = vv;
        }
    }
  }
}

// ------------------------- paired-causal flash attention -------------------
// 256 blocks x 1024 thr (16 warps x 32 q rows, 4 waves/SIMD). Fixed-base
// softmax (p = exp2(s), scores bounded); P-pack via v_permlane32_swap_b32
// (pure VALU register half-swaps, no LDS-pipe shuffles).
static __device__ __forceinline__ u32 pk2(float a, float b) {
  union { __bf16 h[2]; u32 w; } u;
  u.h[0] = (__bf16)a; u.h[1] = (__bf16)b;
  return u.w;
}

#define PACK_FRAG(SRC, OFF, OUT)                                            \
  {                                                                         \
    u32 c01 = pk2(SRC[(OFF) + 0], SRC[(OFF) + 1]);                          \
    u32 c23 = pk2(SRC[(OFF) + 2], SRC[(OFF) + 3]);                          \
    u32 c45 = pk2(SRC[(OFF) + 4], SRC[(OFF) + 5]);                          \
    u32 c67 = pk2(SRC[(OFF) + 6], SRC[(OFF) + 7]);                          \
    asm volatile("v_permlane32_swap_b32 %0, %1" : "+v"(c01), "+v"(c45));    \
    asm volatile("v_permlane32_swap_b32 %0, %1" : "+v"(c23), "+v"(c67));    \
    union { u32 w[4]; bf16x8 v; } fu_;                                      \
    fu_.w[0] = c01; fu_.w[1] = c23; fu_.w[2] = c45; fu_.w[3] = c67;         \
    OUT = fu_.v;                                                            \
  }

#define KOFF(row, cb) ((row) * 128 + ((cb) ^ (((row) & 7) << 4)))
#define VOFF(row, cb) ((row) * 256 + ((cb) ^ (((row) & 15) << 4)))

static __device__ __forceinline__ void qkt(const char* kcs, const bf16x8* qf,
                                           int lq, int hi, f32x16& s0, f32x16& s1) {
  s0 = (f32x16){}; s1 = (f32x16){};
#pragma unroll
  for (int ds = 0; ds < 4; ++ds) {
    bf16x8 kf = *(const bf16x8*)(kcs + KOFF(lq, ds * 32 + hi * 16));
    s0 = MFMA32(kf, qf[ds], s0);
  }
#pragma unroll
  for (int ds = 0; ds < 4; ++ds) {
    bf16x8 kf = *(const bf16x8*)(kcs + KOFF(32 + lq, ds * 32 + hi * 16));
    s1 = MFMA32(kf, qf[ds], s1);
  }
}

// p = exp2(s) with fixed base (no max subtraction); accumulate row sum.
static __device__ __forceinline__ void smexp(f32x16& s0, f32x16& s1,
                                             float& lrun, bf16x8* pa, int hi) {
  float rsp0 = 0.f, rsp1 = 0.f, rsp2 = 0.f, rsp3 = 0.f;
#pragma unroll
  for (int r = 0; r < 4; ++r) {
    float e0 = EXP2(s0[r]), e1 = EXP2(s0[r + 4]);
    float e2 = EXP2(s0[r + 8]), e3 = EXP2(s0[r + 12]);
    s0[r] = e0; s0[r + 4] = e1; s0[r + 8] = e2; s0[r + 12] = e3;
    rsp0 += e0; rsp1 += e1; rsp2 += e2; rsp3 += e3;
  }
#pragma unroll
  for (int r = 0; r < 4; ++r) {
    float e0 = EXP2(s1[r]), e1 = EXP2(s1[r + 4]);
    float e2 = EXP2(s1[r + 8]), e3 = EXP2(s1[r + 12]);
    s1[r] = e0; s1[r + 4] = e1; s1[r + 8] = e2; s1[r + 12] = e3;
    rsp0 += e0; rsp1 += e1; rsp2 += e2; rsp3 += e3;
  }
  float rs = (rsp0 + rsp1) + (rsp2 + rsp3);
  rs += __shfl_xor(rs, 32);
  lrun += rs;
  PACK_FRAG(s0, 0, pa[0])
  PACK_FRAG(s0, 8, pa[1])
  PACK_FRAG(s1, 0, pa[2])
  PACK_FRAG(s1, 8, pa[3])
}

static __device__ __forceinline__ void pv(const char* vc, int vcb0, int lq, int hi,
                                          const bf16x8* pa, f32x16& o0, f32x16& o1) {
#pragma unroll
  for (int fi = 0; fi < 4; ++fi) {
    bf16x8 vf = *(const bf16x8*)(vc + VOFF(lq, vcb0 + fi * 32 + hi * 16));
    o0 = MFMA32(vf, pa[fi], o0);
  }
#pragma unroll
  for (int fi = 0; fi < 4; ++fi) {
    bf16x8 vf = *(const bf16x8*)(vc + VOFF(32 + lq, vcb0 + fi * 32 + hi * 16));
    o1 = MFMA32(vf, pa[fi], o1);
  }
}

__global__ __launch_bounds__(1024) void attn_fwd(const __bf16* __restrict__ Q,
                                                 const __bf16* __restrict__ Kb,
                                                 const __bf16* __restrict__ VTg,
                                                 __bf16* __restrict__ O) {
  __shared__ __align__(16) __bf16 Ks[2][128 * 64];  // 16KB per buf
  __shared__ __align__(16) __bf16 Vs[2][64 * 128];  // 16KB per buf
  const int t = threadIdx.x, w = t >> 6, l = t & 63;
  const int lq = l & 31, hi = l >> 5;
  const int id = blockIdx.x;
  const int bh = (id & 7) + 8 * (id >> 5);  // same-head blocks share an XCD
  const int p = (id >> 3) & 3;
  const int member = (w >> 2) & 1;
  const int ridx = (w & 3) | ((w >> 3) << 2);  // 0..7
  const int qb = member ? 7 - p : p;
  const int q0w = qb * 256 + ridx * 32;
  const int qrow = q0w + lq;
  const size_t kbaseB = (size_t)bh * (2048 * 64 * 2);
  const size_t vbaseB = (size_t)bh * (64 * 2048 * 2);

  const int srow = t >> 3;                               // 0..127 (K rows)
  const int scolb = ((t & 7) * 16) ^ ((srow & 7) << 4);  // inverse swizzle
  const int vrow = t >> 4;                               // 0..63 (V^T rows)
  const int vcolb = ((t & 15) * 16) ^ ((vrow & 15) << 4);
  const char* kgp = (const char*)Kb + kbaseB + (size_t)srow * 128 + scolb;
  const char* vgp = (const char*)VTg + vbaseB + (size_t)vrow * 4096 + vcolb;
  char* kl = (char*)&Ks[0][0] + w * 1024;  // wave-uniform dest
  char* vl = (char*)&Vs[0][0] + w * 1024;

#define STAGE(bi, KT)                                                      \
  {                                                                        \
    GL16(kgp + (size_t)(KT) * 16384, kl + (bi) * 16384);                   \
    GL16(vgp + (size_t)(KT) * 256, vl + (bi) * 16384);                     \
  }

  const size_t qbase = (size_t)bh * (2048 * 64);
  bf16x8 qf[4];
#pragma unroll
  for (int ds = 0; ds < 4; ++ds)
    qf[ds] = *(const bf16x8*)&Q[qbase + (size_t)qrow * 64 + ds * 16 + hi * 8];

  f32x16 o0 = {}, o1 = {};
  float lsum = 0.0f;

  const int nkt = 2 * (7 - p) + 2;  // block-uniform (heavy member bound)
  STAGE(0, 0)
  asm volatile("s_waitcnt vmcnt(0)" ::: "memory");
  __builtin_amdgcn_s_barrier();
  __builtin_amdgcn_sched_barrier(0);
  int cur = 0;
  for (int kt = 0; kt < nkt; ++kt) {
    if (kt + 1 < nkt) STAGE(cur ^ 1, kt + 1)
    const char* kc = (const char*)&Ks[cur][0];
    const char* vc = (const char*)&Vs[cur][0];

#pragma unroll
    for (int sub = 0; sub < 2; ++sub) {
      const int k0 = kt * 128 + sub * 64;
      if (k0 <= q0w + 31) {  // warp-uniform causal skip
        const char* kcs = kc + sub * 8192;
        f32x16 s0, s1;
        __builtin_amdgcn_s_setprio(1);
        qkt(kcs, qf, lq, hi, s0, s1);
        __builtin_amdgcn_s_setprio(0);
        if (k0 + 63 > q0w) {  // causal mask (edge tiles only)
#pragma unroll
          for (int r = 0; r < 16; ++r) {
            int kl_ = k0 + (r & 3) + 8 * (r >> 2) + 4 * hi;
            s0[r] = (kl_ > qrow) ? -1e30f : s0[r];
            s1[r] = (kl_ + 32 > qrow) ? -1e30f : s1[r];
          }
        }
        bf16x8 pa[4];
        smexp(s0, s1, lsum, pa, hi);
        __builtin_amdgcn_s_setprio(1);
        pv(vc, sub * 128, lq, hi, pa, o0, o1);
        __builtin_amdgcn_s_setprio(0);
      }
    }
    asm volatile("s_waitcnt vmcnt(0)" ::: "memory");
    __builtin_amdgcn_s_barrier();
    __builtin_amdgcn_sched_barrier(0);
    cur ^= 1;
  }

  // epilogue: O^T reg r -> d = dtile*32 + (r&3) + 8*(r>>2) + 4*hi, q = lane&31
  const int b = bh >> 4, h = bh & 15;
  float inv = 1.0f / lsum;
  __bf16* orow = O + ((size_t)(b * 2048 + qrow)) * 1024 + h * 64;
#pragma unroll
  for (int rq = 0; rq < 4; ++rq) {
    bf16x4 v0, v1;
#pragma unroll
    for (int e = 0; e < 4; ++e) {
      v0[e] = (__bf16)(o0[rq * 4 + e] * inv);
      v1[e] = (__bf16)(o1[rq * 4 + e] * inv);
    }
    *(bf16x4*)&orow[8 * rq + 4 * hi] = v0;
    *(bf16x4*)&orow[32 + 8 * rq + 4 * hi] = v1;
  }
}

// ---------------------------------------------------------------------------
extern "C" void kernel_launch(void* const* d_in, const int* in_sizes, int n_in,
                              void* d_out, int out_size, void* d_ws, size_t ws_size,
                              hipStream_t stream) {
  const float* x = (const float*)d_in[0];
  const float* wq = (const float*)d_in[1];
  const float* wk = (const float*)d_in[2];
  const float* wv = (const float*)d_in[3];
  const float* wo = (const float*)d_in[4];
  const int* tpos = (const int*)d_in[5];
  float* out = (float*)d_out;

  const size_t SZ_X = 8192u * 1024u * 2u;
  const size_t SZ_W = 1024u * 1024u * 2u;
  const size_t SZ_T = 2048u * 32u * 4u;
  const size_t NEED = SZ_X * 4 + SZ_W * 4 + SZ_T * 2;
  if (ws_size < NEED) return;

  char* p = (char*)d_ws;
  __bf16* xb  = (__bf16*)p; p += SZ_X;   // reused as attention output (AO)
  __bf16* wqb = (__bf16*)p; p += SZ_W;   // 4 weights contiguous (wq|wk|wv|wo)
  __bf16* wkb = (__bf16*)p; p += SZ_W;
  __bf16* wvb = (__bf16*)p; p += SZ_W;
  __bf16* wob = (__bf16*)p; p += SZ_W;
  __bf16* Qb  = (__bf16*)p; p += SZ_X;   // Q | K | V^T contiguous
  __bf16* Kbf = (__bf16*)p; p += SZ_X;
  __bf16* VTg = (__bf16*)p; p += SZ_X;
  float* ct = (float*)p; p += SZ_T;
  float* st = (float*)p; p += SZ_T;
  __bf16* AOb = xb;
  (void)wkb; (void)wvb;

  cvt_all<<<12544, 256, 0, stream>>>(x, wq, wk, wv, wo, xb, wqb, ct, st);

  // fused QKV: B = wq|wk|wv rows (contiguous), N=3072; grid 768 = 3/CU
  gemm8<4><<<768, 512, 0, stream>>>(xb, wqb, (void*)Qb, tpos, ct, st);

  attn_fwd<<<256, 1024, 0, stream>>>(Qb, Kbf, VTg, AOb);

  // out projection: N=1024; grid 256 = 1/CU
  gemm8<3><<<256, 512, 0, stream>>>(AOb, wob, (void*)out, tpos, ct, st);
}

// Round 16
// 155.044 us; speedup vs baseline: 1.0746x; 1.0418x over previous
//
#include <hip/hip_runtime.h>

// ---------------------------------------------------------------------------
// MultiHeadSelfAttentionWithRoPE: B=4, S=2048, D_MODEL=1024, H=16, D_K=64
// fused cvt | 128x128 BK=64 2-blocks/CU QKV GEMM (RoPE fused; V transposed;
// XCD-pinned) | 16-warp paired-causal flash attn (fixed-base softmax,
// permlane P-pack) | 128x128 out GEMM
// ---------------------------------------------------------------------------

typedef float f32x4 __attribute__((ext_vector_type(4)));
typedef float f32x16 __attribute__((ext_vector_type(16)));
typedef __bf16 bf16x8 __attribute__((ext_vector_type(8)));
typedef __bf16 bf16x4 __attribute__((ext_vector_type(4)));
typedef unsigned int u32;

#define MFMA16(a, b, c) __builtin_amdgcn_mfma_f32_16x16x32_bf16((a), (b), (c), 0, 0, 0)
#define MFMA32(a, b, c) __builtin_amdgcn_mfma_f32_32x32x16_bf16((a), (b), (c), 0, 0, 0)

#define GL16(gp, lp)                                                        \
  __builtin_amdgcn_global_load_lds(                                         \
      (const __attribute__((address_space(1))) void*)(gp),                  \
      (__attribute__((address_space(3))) void*)(lp), 16, 0, 0)

#define EXP2(x) __builtin_amdgcn_exp2f(x)
#define QSCALE 0.18033688011112042f

// ---------------- fused cvt: x (f32->bf16), 4 weights, RoPE table ----------
__global__ void cvt_all(const float* __restrict__ x,
                        const float* __restrict__ wq, const float* __restrict__ wk,
                        const float* __restrict__ wv, const float* __restrict__ wo,
                        __bf16* __restrict__ xb, __bf16* __restrict__ wdst,
                        float* __restrict__ ct, float* __restrict__ st) {
  const int bid = blockIdx.x;
  if (bid < 8192) {
    int i = bid * 256 + threadIdx.x;
    float4 v = ((const float4*)x)[i];
    bf16x4 o;
    o[0] = (__bf16)v.x; o[1] = (__bf16)v.y; o[2] = (__bf16)v.z; o[3] = (__bf16)v.w;
    ((bf16x4*)xb)[i] = o;
  } else if (bid < 12288) {
    int i = (bid - 8192) * 256 + threadIdx.x;
    int sel = i >> 18;
    const float* src = sel == 0 ? wq : sel == 1 ? wk : sel == 2 ? wv : wo;
    int j = i & 262143;
    float4 v = ((const float4*)src)[j];
    bf16x4 o;
    o[0] = (__bf16)v.x; o[1] = (__bf16)v.y; o[2] = (__bf16)v.z; o[3] = (__bf16)v.w;
    ((bf16x4*)wdst)[i] = o;
  } else {
    int i = (bid - 12288) * 256 + threadIdx.x;  // 65536 = 2048*32
    int pos = i >> 5, f = i & 31;
    float inv = powf(10000.0f, -(float)f * (1.0f / 32.0f));
    float a = (float)pos * inv;
    ct[i] = cosf(a);
    st[i] = sinf(a);
  }
}

// --------- 128x128 BK=64 GEMM (2 blocks/CU): C = A(8192xK) * B(NxK)^T ------
// 256 thr = 4 waves (2M x 2N), per-wave 64x64. LDS 64KB: A 2x16KB, B 2x16KB.
// 1 barrier/K-tile; cross-block wave overlap hides the vmcnt drain.
// Block map: XCD k owns bm {8k..8k+7} (A panels 2MB, L2-pinned), bn sweeps.
// MODE 4: fused QKV (N=3072): seg 0=Q(RoPE+QSCALE) 1=K(RoPE) 2=V^T
// MODE 3: out f32 (N=1024)
template <int MODE>
__global__ __launch_bounds__(256, 2) void gemm8(const __bf16* __restrict__ A,
                                                const __bf16* __restrict__ Bw,
                                                void* __restrict__ Cout,
                                                const int* __restrict__ tpos,
                                                const float* __restrict__ ct,
                                                const float* __restrict__ st) {
  __shared__ __align__(16) char LB[65536];  // A 2x16KB | B 2x16KB
  const int nk = 16;  // K=1024 / BK=64
  const int t = threadIdx.x, w = t >> 6, l = t & 63;
  const int lr = l & 15, lg = l >> 4;
  const int wr = w >> 1, wc = w & 1;
  const int id = blockIdx.x;
  const int xcd = id & 7, i = id >> 3;
  const int bm = xcd * 8 + (i & 7);  // 8 panels per XCD, L2-resident
  const int bn = i >> 3;             // sweeps 0..23 (MODE4) / 0..7 (MODE3)

  const int srow = t >> 3;                               // 0..31
  const int scbs = ((t & 7) * 16) ^ ((srow & 7) << 4);   // inverse swizzle
  const char* Ag = (const char*)A + (size_t)(bm * 128 + srow) * 2048 + scbs;
  const char* Bg = (const char*)Bw + (size_t)(bn * 128 + srow) * 2048 + scbs;
  char* lw = LB + w * 1024;  // wave-uniform dest base

#define STAGE_AB(d, KT)                                                     \
  {                                                                         \
    GL16(Ag + (KT) * 128, lw + (d) * 16384);                                \
    GL16(Ag + (KT) * 128 + (size_t)32 * 2048, lw + (d) * 16384 + 4096);     \
    GL16(Ag + (KT) * 128 + (size_t)64 * 2048, lw + (d) * 16384 + 8192);     \
    GL16(Ag + (KT) * 128 + (size_t)96 * 2048, lw + (d) * 16384 + 12288);    \
    GL16(Bg + (KT) * 128, lw + 32768 + (d) * 16384);                        \
    GL16(Bg + (KT) * 128 + (size_t)32 * 2048, lw + 32768 + (d) * 16384 + 4096); \
    GL16(Bg + (KT) * 128 + (size_t)64 * 2048, lw + 32768 + (d) * 16384 + 8192); \
    GL16(Bg + (KT) * 128 + (size_t)96 * 2048, lw + 32768 + (d) * 16384 + 12288); \
  }

  const int sw = (lr & 7) << 4;
  const int c0 = (lg * 16) ^ sw;       // kk=0
  const int c1 = (64 + lg * 16) ^ sw;  // kk=1

  f32x4 acc[4][4] = {};

  STAGE_AB(0, 0)
  asm volatile("s_waitcnt vmcnt(0)" ::: "memory");
  __builtin_amdgcn_s_barrier();
  __builtin_amdgcn_sched_barrier(0);

  for (int kt = 0; kt < nk; ++kt) {
    const int X = kt & 1;
    if (kt + 1 < nk) STAGE_AB(X ^ 1, kt + 1)
    const char* Ab = LB + X * 16384;
    const char* Bb = LB + 32768 + X * 16384;
    bf16x8 af[4][2], bf[4][2];
#pragma unroll
    for (int m = 0; m < 4; ++m) {
      const int ar = (wr * 64 + m * 16 + lr) * 128;
      af[m][0] = *(const bf16x8*)(Ab + ar + c0);
      af[m][1] = *(const bf16x8*)(Ab + ar + c1);
    }
#pragma unroll
    for (int n = 0; n < 4; ++n) {
      const int br = (wc * 64 + n * 16 + lr) * 128;
      bf[n][0] = *(const bf16x8*)(Bb + br + c0);
      bf[n][1] = *(const bf16x8*)(Bb + br + c1);
    }
    __builtin_amdgcn_s_setprio(1);
#pragma unroll
    for (int m = 0; m < 4; ++m)
#pragma unroll
      for (int n = 0; n < 4; ++n)
#pragma unroll
        for (int kk = 0; kk < 2; ++kk)
          acc[m][n] = MFMA16(af[m][kk], bf[n][kk], acc[m][n]);
    __builtin_amdgcn_s_setprio(0);
    asm volatile("s_waitcnt vmcnt(0)" ::: "memory");
    __builtin_amdgcn_s_barrier();
    __builtin_amdgcn_sched_barrier(0);
  }

  // ---------------- epilogue ----------------
  if (MODE == 3) {
    float* outp = (float*)Cout;
#pragma unroll
    for (int m = 0; m < 4; ++m)
#pragma unroll
      for (int n = 0; n < 4; ++n)
#pragma unroll
        for (int e = 0; e < 4; ++e) {
          const int grow = bm * 128 + wr * 64 + m * 16 + lg * 4 + e;
          const int gcol = bn * 128 + wc * 64 + n * 16 + lr;
          outp[(size_t)grow * 1024 + gcol] = acc[m][n][e];
        }
  } else {
    const int seg = bn >> 3;  // 0=Q 1=K 2=V
    const int bnn = bn & 7;
    if (seg < 2) {
      const int h = bnn * 2 + wc;
      __bf16* base = (__bf16*)Cout + (size_t)seg * 8388608;
#pragma unroll
      for (int m = 0; m < 4; ++m)
#pragma unroll
        for (int e = 0; e < 4; ++e) {
          const int grow = bm * 128 + wr * 64 + m * 16 + lg * 4 + e;
          const int pos = tpos[grow];
          const int b = grow >> 11, s = grow & 2047;
          __bf16* orow = &base[(((size_t)(b * 16 + h)) * 2048 + s) * 64];
#pragma unroll
          for (int j = 0; j < 2; ++j) {
            const int dd = j * 16 + lr;
            const float c = ct[pos * 32 + dd], sn = st[pos * 32 + dd];
            float x1 = acc[m][j][e], x2 = acc[m][j + 2][e];
            float o1 = x1 * c - x2 * sn;
            float o2 = x2 * c + x1 * sn;
            if (seg == 0) { o1 *= QSCALE; o2 *= QSCALE; }
            orow[dd] = (__bf16)o1;
            orow[dd + 32] = (__bf16)o2;
          }
        }
    } else {
      __bf16* base = (__bf16*)Cout + 16777216;
#pragma unroll
      for (int m = 0; m < 4; ++m)
#pragma unroll
        for (int n = 0; n < 4; ++n) {
          const int grow0 = bm * 128 + wr * 64 + m * 16 + lg * 4;
          const int gcs = bnn * 128 + wc * 64 + n * 16 + lr;
          const int b = grow0 >> 11, s = grow0 & 2047;
          const int h = gcs >> 6, d = gcs & 63;
          bf16x4 vv;
#pragma unroll
          for (int e = 0; e < 4; ++e) vv[e] = (__bf16)acc[m][n][e];
          *(bf16x4*)&base[(((size_t)(b * 16 + h)) * 64 + d) * 2048 + s] = vv;
        }
    }
  }
}

// ------------------------- paired-causal flash attention -------------------
// 256 blocks x 1024 thr (16 warps x 32 q rows, 4 waves/SIMD). Fixed-base
// softmax (p = exp2(s), scores bounded); P-pack via v_permlane32_swap_b32.
static __device__ __forceinline__ u32 pk2(float a, float b) {
  union { __bf16 h[2]; u32 w; } u;
  u.h[0] = (__bf16)a; u.h[1] = (__bf16)b;
  return u.w;
}

#define PACK_FRAG(SRC, OFF, OUT)                                            \
  {                                                                         \
    u32 c01 = pk2(SRC[(OFF) + 0], SRC[(OFF) + 1]);                          \
    u32 c23 = pk2(SRC[(OFF) + 2], SRC[(OFF) + 3]);                          \
    u32 c45 = pk2(SRC[(OFF) + 4], SRC[(OFF) + 5]);                          \
    u32 c67 = pk2(SRC[(OFF) + 6], SRC[(OFF) + 7]);                          \
    asm volatile("v_permlane32_swap_b32 %0, %1" : "+v"(c01), "+v"(c45));    \
    asm volatile("v_permlane32_swap_b32 %0, %1" : "+v"(c23), "+v"(c67));    \
    union { u32 w[4]; bf16x8 v; } fu_;                                      \
    fu_.w[0] = c01; fu_.w[1] = c23; fu_.w[2] = c45; fu_.w[3] = c67;         \
    OUT = fu_.v;                                                            \
  }

#define KOFF(row, cb) ((row) * 128 + ((cb) ^ (((row) & 7) << 4)))
#define VOFF(row, cb) ((row) * 256 + ((cb) ^ (((row) & 15) << 4)))

static __device__ __forceinline__ void qkt(const char* kcs, const bf16x8* qf,
                                           int lq, int hi, f32x16& s0, f32x16& s1) {
  s0 = (f32x16){}; s1 = (f32x16){};
#pragma unroll
  for (int ds = 0; ds < 4; ++ds) {
    bf16x8 kf = *(const bf16x8*)(kcs + KOFF(lq, ds * 32 + hi * 16));
    s0 = MFMA32(kf, qf[ds], s0);
  }
#pragma unroll
  for (int ds = 0; ds < 4; ++ds) {
    bf16x8 kf = *(const bf16x8*)(kcs + KOFF(32 + lq, ds * 32 + hi * 16));
    s1 = MFMA32(kf, qf[ds], s1);
  }
}

// p = exp2(s) with fixed base (no max subtraction); accumulate row sum.
static __device__ __forceinline__ void smexp(f32x16& s0, f32x16& s1,
                                             float& lrun, bf16x8* pa, int hi) {
  float rsp0 = 0.f, rsp1 = 0.f, rsp2 = 0.f, rsp3 = 0.f;
#pragma unroll
  for (int r = 0; r < 4; ++r) {
    float e0 = EXP2(s0[r]), e1 = EXP2(s0[r + 4]);
    float e2 = EXP2(s0[r + 8]), e3 = EXP2(s0[r + 12]);
    s0[r] = e0; s0[r + 4] = e1; s0[r + 8] = e2; s0[r + 12] = e3;
    rsp0 += e0; rsp1 += e1; rsp2 += e2; rsp3 += e3;
  }
#pragma unroll
  for (int r = 0; r < 4; ++r) {
    float e0 = EXP2(s1[r]), e1 = EXP2(s1[r + 4]);
    float e2 = EXP2(s1[r + 8]), e3 = EXP2(s1[r + 12]);
    s1[r] = e0; s1[r + 4] = e1; s1[r + 8] = e2; s1[r + 12] = e3;
    rsp0 += e0; rsp1 += e1; rsp2 += e2; rsp3 += e3;
  }
  float rs = (rsp0 + rsp1) + (rsp2 + rsp3);
  rs += __shfl_xor(rs, 32);
  lrun += rs;
  PACK_FRAG(s0, 0, pa[0])
  PACK_FRAG(s0, 8, pa[1])
  PACK_FRAG(s1, 0, pa[2])
  PACK_FRAG(s1, 8, pa[3])
}

static __device__ __forceinline__ void pv(const char* vc, int vcb0, int lq, int hi,
                                          const bf16x8* pa, f32x16& o0, f32x16& o1) {
#pragma unroll
  for (int fi = 0; fi < 4; ++fi) {
    bf16x8 vf = *(const bf16x8*)(vc + VOFF(lq, vcb0 + fi * 32 + hi * 16));
    o0 = MFMA32(vf, pa[fi], o0);
  }
#pragma unroll
  for (int fi = 0; fi < 4; ++fi) {
    bf16x8 vf = *(const bf16x8*)(vc + VOFF(32 + lq, vcb0 + fi * 32 + hi * 16));
    o1 = MFMA32(vf, pa[fi], o1);
  }
}

__global__ __launch_bounds__(1024) void attn_fwd(const __bf16* __restrict__ Q,
                                                 const __bf16* __restrict__ Kb,
                                                 const __bf16* __restrict__ VTg,
                                                 __bf16* __restrict__ O) {
  __shared__ __align__(16) __bf16 Ks[2][128 * 64];  // 16KB per buf
  __shared__ __align__(16) __bf16 Vs[2][64 * 128];  // 16KB per buf
  const int t = threadIdx.x, w = t >> 6, l = t & 63;
  const int lq = l & 31, hi = l >> 5;
  const int id = blockIdx.x;
  const int bh = (id & 7) + 8 * (id >> 5);  // same-head blocks share an XCD
  const int p = (id >> 3) & 3;
  const int member = (w >> 2) & 1;
  const int ridx = (w & 3) | ((w >> 3) << 2);  // 0..7
  const int qb = member ? 7 - p : p;
  const int q0w = qb * 256 + ridx * 32;
  const int qrow = q0w + lq;
  const size_t kbaseB = (size_t)bh * (2048 * 64 * 2);
  const size_t vbaseB = (size_t)bh * (64 * 2048 * 2);

  const int srow = t >> 3;                               // 0..127 (K rows)
  const int scolb = ((t & 7) * 16) ^ ((srow & 7) << 4);  // inverse swizzle
  const int vrow = t >> 4;                               // 0..63 (V^T rows)
  const int vcolb = ((t & 15) * 16) ^ ((vrow & 15) << 4);
  const char* kgp = (const char*)Kb + kbaseB + (size_t)srow * 128 + scolb;
  const char* vgp = (const char*)VTg + vbaseB + (size_t)vrow * 4096 + vcolb;
  char* kl = (char*)&Ks[0][0] + w * 1024;  // wave-uniform dest
  char* vl = (char*)&Vs[0][0] + w * 1024;

#define STAGE(bi, KT)                                                      \
  {                                                                        \
    GL16(kgp + (size_t)(KT) * 16384, kl + (bi) * 16384);                   \
    GL16(vgp + (size_t)(KT) * 256, vl + (bi) * 16384);                     \
  }

  const size_t qbase = (size_t)bh * (2048 * 64);
  bf16x8 qf[4];
#pragma unroll
  for (int ds = 0; ds < 4; ++ds)
    qf[ds] = *(const bf16x8*)&Q[qbase + (size_t)qrow * 64 + ds * 16 + hi * 8];

  f32x16 o0 = {}, o1 = {};
  float lsum = 0.0f;

  const int nkt = 2 * (7 - p) + 2;  // block-uniform (heavy member bound)
  STAGE(0, 0)
  asm volatile("s_waitcnt vmcnt(0)" ::: "memory");
  __builtin_amdgcn_s_barrier();
  __builtin_amdgcn_sched_barrier(0);
  int cur = 0;
  for (int kt = 0; kt < nkt; ++kt) {
    if (kt + 1 < nkt) STAGE(cur ^ 1, kt + 1)
    const char* kc = (const char*)&Ks[cur][0];
    const char* vc = (const char*)&Vs[cur][0];

#pragma unroll
    for (int sub = 0; sub < 2; ++sub) {
      const int k0 = kt * 128 + sub * 64;
      if (k0 <= q0w + 31) {  // warp-uniform causal skip
        const char* kcs = kc + sub * 8192;
        f32x16 s0, s1;
        __builtin_amdgcn_s_setprio(1);
        qkt(kcs, qf, lq, hi, s0, s1);
        __builtin_amdgcn_s_setprio(0);
        if (k0 + 63 > q0w) {  // causal mask (edge tiles only)
#pragma unroll
          for (int r = 0; r < 16; ++r) {
            int kl_ = k0 + (r & 3) + 8 * (r >> 2) + 4 * hi;
            s0[r] = (kl_ > qrow) ? -1e30f : s0[r];
            s1[r] = (kl_ + 32 > qrow) ? -1e30f : s1[r];
          }
        }
        bf16x8 pa[4];
        smexp(s0, s1, lsum, pa, hi);
        __builtin_amdgcn_s_setprio(1);
        pv(vc, sub * 128, lq, hi, pa, o0, o1);
        __builtin_amdgcn_s_setprio(0);
      }
    }
    asm volatile("s_waitcnt vmcnt(0)" ::: "memory");
    __builtin_amdgcn_s_barrier();
    __builtin_amdgcn_sched_barrier(0);
    cur ^= 1;
  }

  // epilogue: O^T reg r -> d = dtile*32 + (r&3) + 8*(r>>2) + 4*hi, q = lane&31
  const int b = bh >> 4, h = bh & 15;
  float inv = 1.0f / lsum;
  __bf16* orow = O + ((size_t)(b * 2048 + qrow)) * 1024 + h * 64;
#pragma unroll
  for (int rq = 0; rq < 4; ++rq) {
    bf16x4 v0, v1;
#pragma unroll
    for (int e = 0; e < 4; ++e) {
      v0[e] = (__bf16)(o0[rq * 4 + e] * inv);
      v1[e] = (__bf16)(o1[rq * 4 + e] * inv);
    }
    *(bf16x4*)&orow[8 * rq + 4 * hi] = v0;
    *(bf16x4*)&orow[32 + 8 * rq + 4 * hi] = v1;
  }
}

// ---------------------------------------------------------------------------
extern "C" void kernel_launch(void* const* d_in, const int* in_sizes, int n_in,
                              void* d_out, int out_size, void* d_ws, size_t ws_size,
                              hipStream_t stream) {
  const float* x = (const float*)d_in[0];
  const float* wq = (const float*)d_in[1];
  const float* wk = (const float*)d_in[2];
  const float* wv = (const float*)d_in[3];
  const float* wo = (const float*)d_in[4];
  const int* tpos = (const int*)d_in[5];
  float* out = (float*)d_out;

  const size_t SZ_X = 8192u * 1024u * 2u;
  const size_t SZ_W = 1024u * 1024u * 2u;
  const size_t SZ_T = 2048u * 32u * 4u;
  const size_t NEED = SZ_X * 4 + SZ_W * 4 + SZ_T * 2;
  if (ws_size < NEED) return;

  char* p = (char*)d_ws;
  __bf16* xb  = (__bf16*)p; p += SZ_X;   // reused as attention output (AO)
  __bf16* wqb = (__bf16*)p; p += SZ_W;   // 4 weights contiguous (wq|wk|wv|wo)
  __bf16* wkb = (__bf16*)p; p += SZ_W;
  __bf16* wvb = (__bf16*)p; p += SZ_W;
  __bf16* wob = (__bf16*)p; p += SZ_W;
  __bf16* Qb  = (__bf16*)p; p += SZ_X;   // Q | K | V^T contiguous
  __bf16* Kbf = (__bf16*)p; p += SZ_X;
  __bf16* VTg = (__bf16*)p; p += SZ_X;
  float* ct = (float*)p; p += SZ_T;
  float* st = (float*)p; p += SZ_T;
  __bf16* AOb = xb;
  (void)wkb; (void)wvb;

  cvt_all<<<12544, 256, 0, stream>>>(x, wq, wk, wv, wo, xb, wqb, ct, st);

  // fused QKV: B = wq|wk|wv rows (contiguous), N=3072; grid 1536 = 6/CU
  gemm8<4><<<1536, 256, 0, stream>>>(xb, wqb, (void*)Qb, tpos, ct, st);

  attn_fwd<<<256, 1024, 0, stream>>>(Qb, Kbf, VTg, AOb);

  // out projection: N=1024; grid 512 = 2/CU
  gemm8<3><<<512, 256, 0, stream>>>(AOb, wob, (void*)out, tpos, ct, st);
}

// Round 17
// 154.963 us; speedup vs baseline: 1.0752x; 1.0005x over previous
//
#include <hip/hip_runtime.h>

// ---------------------------------------------------------------------------
// MultiHeadSelfAttentionWithRoPE: B=4, S=2048, D_MODEL=1024, H=16, D_K=64
// fused cvt | 128x128 BK=64 2-blocks/CU QKV GEMM (RoPE fused; V transposed;
// XCD-pinned) | 16-warp paired-causal flash attn (3-buf counted-vmcnt stage,
// fixed-base softmax, permlane P-pack) | 128x128 out GEMM
// ---------------------------------------------------------------------------

typedef float f32x4 __attribute__((ext_vector_type(4)));
typedef float f32x16 __attribute__((ext_vector_type(16)));
typedef __bf16 bf16x8 __attribute__((ext_vector_type(8)));
typedef __bf16 bf16x4 __attribute__((ext_vector_type(4)));
typedef unsigned int u32;

#define MFMA16(a, b, c) __builtin_amdgcn_mfma_f32_16x16x32_bf16((a), (b), (c), 0, 0, 0)
#define MFMA32(a, b, c) __builtin_amdgcn_mfma_f32_32x32x16_bf16((a), (b), (c), 0, 0, 0)

#define GL16(gp, lp)                                                        \
  __builtin_amdgcn_global_load_lds(                                         \
      (const __attribute__((address_space(1))) void*)(gp),                  \
      (__attribute__((address_space(3))) void*)(lp), 16, 0, 0)

#define EXP2(x) __builtin_amdgcn_exp2f(x)
#define QSCALE 0.18033688011112042f

// ---------------- fused cvt: x (f32->bf16), 4 weights, RoPE table ----------
__global__ void cvt_all(const float* __restrict__ x,
                        const float* __restrict__ wq, const float* __restrict__ wk,
                        const float* __restrict__ wv, const float* __restrict__ wo,
                        __bf16* __restrict__ xb, __bf16* __restrict__ wdst,
                        float* __restrict__ ct, float* __restrict__ st) {
  const int bid = blockIdx.x;
  if (bid < 8192) {
    int i = bid * 256 + threadIdx.x;
    float4 v = ((const float4*)x)[i];
    bf16x4 o;
    o[0] = (__bf16)v.x; o[1] = (__bf16)v.y; o[2] = (__bf16)v.z; o[3] = (__bf16)v.w;
    ((bf16x4*)xb)[i] = o;
  } else if (bid < 12288) {
    int i = (bid - 8192) * 256 + threadIdx.x;
    int sel = i >> 18;
    const float* src = sel == 0 ? wq : sel == 1 ? wk : sel == 2 ? wv : wo;
    int j = i & 262143;
    float4 v = ((const float4*)src)[j];
    bf16x4 o;
    o[0] = (__bf16)v.x; o[1] = (__bf16)v.y; o[2] = (__bf16)v.z; o[3] = (__bf16)v.w;
    ((bf16x4*)wdst)[i] = o;
  } else {
    int i = (bid - 12288) * 256 + threadIdx.x;  // 65536 = 2048*32
    int pos = i >> 5, f = i & 31;
    float inv = powf(10000.0f, -(float)f * (1.0f / 32.0f));
    float a = (float)pos * inv;
    ct[i] = cosf(a);
    st[i] = sinf(a);
  }
}

// --------- 128x128 BK=64 GEMM (2 blocks/CU): C = A(8192xK) * B(NxK)^T ------
template <int MODE>
__global__ __launch_bounds__(256, 2) void gemm8(const __bf16* __restrict__ A,
                                                const __bf16* __restrict__ Bw,
                                                void* __restrict__ Cout,
                                                const int* __restrict__ tpos,
                                                const float* __restrict__ ct,
                                                const float* __restrict__ st) {
  __shared__ __align__(16) char LB[65536];  // A 2x16KB | B 2x16KB
  const int nk = 16;  // K=1024 / BK=64
  const int t = threadIdx.x, w = t >> 6, l = t & 63;
  const int lr = l & 15, lg = l >> 4;
  const int wr = w >> 1, wc = w & 1;
  const int id = blockIdx.x;
  const int xcd = id & 7, i = id >> 3;
  const int bm = xcd * 8 + (i & 7);  // 8 panels per XCD, L2-resident
  const int bn = i >> 3;             // sweeps 0..23 (MODE4) / 0..7 (MODE3)

  const int srow = t >> 3;                               // 0..31
  const int scbs = ((t & 7) * 16) ^ ((srow & 7) << 4);   // inverse swizzle
  const char* Ag = (const char*)A + (size_t)(bm * 128 + srow) * 2048 + scbs;
  const char* Bg = (const char*)Bw + (size_t)(bn * 128 + srow) * 2048 + scbs;
  char* lw = LB + w * 1024;  // wave-uniform dest base

#define STAGE_AB(d, KT)                                                     \
  {                                                                         \
    GL16(Ag + (KT) * 128, lw + (d) * 16384);                                \
    GL16(Ag + (KT) * 128 + (size_t)32 * 2048, lw + (d) * 16384 + 4096);     \
    GL16(Ag + (KT) * 128 + (size_t)64 * 2048, lw + (d) * 16384 + 8192);     \
    GL16(Ag + (KT) * 128 + (size_t)96 * 2048, lw + (d) * 16384 + 12288);    \
    GL16(Bg + (KT) * 128, lw + 32768 + (d) * 16384);                        \
    GL16(Bg + (KT) * 128 + (size_t)32 * 2048, lw + 32768 + (d) * 16384 + 4096); \
    GL16(Bg + (KT) * 128 + (size_t)64 * 2048, lw + 32768 + (d) * 16384 + 8192); \
    GL16(Bg + (KT) * 128 + (size_t)96 * 2048, lw + 32768 + (d) * 16384 + 12288); \
  }

  const int sw = (lr & 7) << 4;
  const int c0 = (lg * 16) ^ sw;       // kk=0
  const int c1 = (64 + lg * 16) ^ sw;  // kk=1

  f32x4 acc[4][4] = {};

  STAGE_AB(0, 0)
  asm volatile("s_waitcnt vmcnt(0)" ::: "memory");
  __builtin_amdgcn_s_barrier();
  __builtin_amdgcn_sched_barrier(0);

  for (int kt = 0; kt < nk; ++kt) {
    const int X = kt & 1;
    if (kt + 1 < nk) STAGE_AB(X ^ 1, kt + 1)
    const char* Ab = LB + X * 16384;
    const char* Bb = LB + 32768 + X * 16384;
    bf16x8 af[4][2], bf[4][2];
#pragma unroll
    for (int m = 0; m < 4; ++m) {
      const int ar = (wr * 64 + m * 16 + lr) * 128;
      af[m][0] = *(const bf16x8*)(Ab + ar + c0);
      af[m][1] = *(const bf16x8*)(Ab + ar + c1);
    }
#pragma unroll
    for (int n = 0; n < 4; ++n) {
      const int br = (wc * 64 + n * 16 + lr) * 128;
      bf[n][0] = *(const bf16x8*)(Bb + br + c0);
      bf[n][1] = *(const bf16x8*)(Bb + br + c1);
    }
    __builtin_amdgcn_s_setprio(1);
#pragma unroll
    for (int m = 0; m < 4; ++m)
#pragma unroll
      for (int n = 0; n < 4; ++n)
#pragma unroll
        for (int kk = 0; kk < 2; ++kk)
          acc[m][n] = MFMA16(af[m][kk], bf[n][kk], acc[m][n]);
    __builtin_amdgcn_s_setprio(0);
    asm volatile("s_waitcnt vmcnt(0)" ::: "memory");
    __builtin_amdgcn_s_barrier();
    __builtin_amdgcn_sched_barrier(0);
  }

  // ---------------- epilogue ----------------
  if (MODE == 3) {
    float* outp = (float*)Cout;
#pragma unroll
    for (int m = 0; m < 4; ++m)
#pragma unroll
      for (int n = 0; n < 4; ++n)
#pragma unroll
        for (int e = 0; e < 4; ++e) {
          const int grow = bm * 128 + wr * 64 + m * 16 + lg * 4 + e;
          const int gcol = bn * 128 + wc * 64 + n * 16 + lr;
          outp[(size_t)grow * 1024 + gcol] = acc[m][n][e];
        }
  } else {
    const int seg = bn >> 3;  // 0=Q 1=K 2=V
    const int bnn = bn & 7;
    if (seg < 2) {
      const int h = bnn * 2 + wc;
      __bf16* base = (__bf16*)Cout + (size_t)seg * 8388608;
#pragma unroll
      for (int m = 0; m < 4; ++m)
#pragma unroll
        for (int e = 0; e < 4; ++e) {
          const int grow = bm * 128 + wr * 64 + m * 16 + lg * 4 + e;
          const int pos = tpos[grow];
          const int b = grow >> 11, s = grow & 2047;
          __bf16* orow = &base[(((size_t)(b * 16 + h)) * 2048 + s) * 64];
#pragma unroll
          for (int j = 0; j < 2; ++j) {
            const int dd = j * 16 + lr;
            const float c = ct[pos * 32 + dd], sn = st[pos * 32 + dd];
            float x1 = acc[m][j][e], x2 = acc[m][j + 2][e];
            float o1 = x1 * c - x2 * sn;
            float o2 = x2 * c + x1 * sn;
            if (seg == 0) { o1 *= QSCALE; o2 *= QSCALE; }
            orow[dd] = (__bf16)o1;
            orow[dd + 32] = (__bf16)o2;
          }
        }
    } else {
      __bf16* base = (__bf16*)Cout + 16777216;
#pragma unroll
      for (int m = 0; m < 4; ++m)
#pragma unroll
        for (int n = 0; n < 4; ++n) {
          const int grow0 = bm * 128 + wr * 64 + m * 16 + lg * 4;
          const int gcs = bnn * 128 + wc * 64 + n * 16 + lr;
          const int b = grow0 >> 11, s = grow0 & 2047;
          const int h = gcs >> 6, d = gcs & 63;
          bf16x4 vv;
#pragma unroll
          for (int e = 0; e < 4; ++e) vv[e] = (__bf16)acc[m][n][e];
          *(bf16x4*)&base[(((size_t)(b * 16 + h)) * 64 + d) * 2048 + s] = vv;
        }
    }
  }
}

// ------------------------- paired-causal flash attention -------------------
// 256 blocks x 1024 thr (16 warps x 32 q rows, 4 waves/SIMD). 3-buffer
// staging with counted vmcnt(2): end-of-iter waits only loads issued a full
// iteration earlier -- never drains the fresh prefetch. Fixed-base softmax;
// P-pack via v_permlane32_swap_b32.
static __device__ __forceinline__ u32 pk2(float a, float b) {
  union { __bf16 h[2]; u32 w; } u;
  u.h[0] = (__bf16)a; u.h[1] = (__bf16)b;
  return u.w;
}

#define PACK_FRAG(SRC, OFF, OUT)                                            \
  {                                                                         \
    u32 c01 = pk2(SRC[(OFF) + 0], SRC[(OFF) + 1]);                          \
    u32 c23 = pk2(SRC[(OFF) + 2], SRC[(OFF) + 3]);                          \
    u32 c45 = pk2(SRC[(OFF) + 4], SRC[(OFF) + 5]);                          \
    u32 c67 = pk2(SRC[(OFF) + 6], SRC[(OFF) + 7]);                          \
    asm volatile("v_permlane32_swap_b32 %0, %1" : "+v"(c01), "+v"(c45));    \
    asm volatile("v_permlane32_swap_b32 %0, %1" : "+v"(c23), "+v"(c67));    \
    union { u32 w[4]; bf16x8 v; } fu_;                                      \
    fu_.w[0] = c01; fu_.w[1] = c23; fu_.w[2] = c45; fu_.w[3] = c67;         \
    OUT = fu_.v;                                                            \
  }

#define KOFF(row, cb) ((row) * 128 + ((cb) ^ (((row) & 7) << 4)))
#define VOFF(row, cb) ((row) * 256 + ((cb) ^ (((row) & 15) << 4)))

static __device__ __forceinline__ void qkt(const char* kcs, const bf16x8* qf,
                                           int lq, int hi, f32x16& s0, f32x16& s1) {
  s0 = (f32x16){}; s1 = (f32x16){};
#pragma unroll
  for (int ds = 0; ds < 4; ++ds) {
    bf16x8 kf = *(const bf16x8*)(kcs + KOFF(lq, ds * 32 + hi * 16));
    s0 = MFMA32(kf, qf[ds], s0);
  }
#pragma unroll
  for (int ds = 0; ds < 4; ++ds) {
    bf16x8 kf = *(const bf16x8*)(kcs + KOFF(32 + lq, ds * 32 + hi * 16));
    s1 = MFMA32(kf, qf[ds], s1);
  }
}

// p = exp2(s) with fixed base (no max subtraction); accumulate row sum.
static __device__ __forceinline__ void smexp(f32x16& s0, f32x16& s1,
                                             float& lrun, bf16x8* pa, int hi) {
  float rsp0 = 0.f, rsp1 = 0.f, rsp2 = 0.f, rsp3 = 0.f;
#pragma unroll
  for (int r = 0; r < 4; ++r) {
    float e0 = EXP2(s0[r]), e1 = EXP2(s0[r + 4]);
    float e2 = EXP2(s0[r + 8]), e3 = EXP2(s0[r + 12]);
    s0[r] = e0; s0[r + 4] = e1; s0[r + 8] = e2; s0[r + 12] = e3;
    rsp0 += e0; rsp1 += e1; rsp2 += e2; rsp3 += e3;
  }
#pragma unroll
  for (int r = 0; r < 4; ++r) {
    float e0 = EXP2(s1[r]), e1 = EXP2(s1[r + 4]);
    float e2 = EXP2(s1[r + 8]), e3 = EXP2(s1[r + 12]);
    s1[r] = e0; s1[r + 4] = e1; s1[r + 8] = e2; s1[r + 12] = e3;
    rsp0 += e0; rsp1 += e1; rsp2 += e2; rsp3 += e3;
  }
  float rs = (rsp0 + rsp1) + (rsp2 + rsp3);
  rs += __shfl_xor(rs, 32);
  lrun += rs;
  PACK_FRAG(s0, 0, pa[0])
  PACK_FRAG(s0, 8, pa[1])
  PACK_FRAG(s1, 0, pa[2])
  PACK_FRAG(s1, 8, pa[3])
}

static __device__ __forceinline__ void pv(const char* vc, int vcb0, int lq, int hi,
                                          const bf16x8* pa, f32x16& o0, f32x16& o1) {
#pragma unroll
  for (int fi = 0; fi < 4; ++fi) {
    bf16x8 vf = *(const bf16x8*)(vc + VOFF(lq, vcb0 + fi * 32 + hi * 16));
    o0 = MFMA32(vf, pa[fi], o0);
  }
#pragma unroll
  for (int fi = 0; fi < 4; ++fi) {
    bf16x8 vf = *(const bf16x8*)(vc + VOFF(32 + lq, vcb0 + fi * 32 + hi * 16));
    o1 = MFMA32(vf, pa[fi], o1);
  }
}

__global__ __launch_bounds__(1024) void attn_fwd(const __bf16* __restrict__ Q,
                                                 const __bf16* __restrict__ Kb,
                                                 const __bf16* __restrict__ VTg,
                                                 __bf16* __restrict__ O) {
  __shared__ __align__(16) __bf16 Ks[3][128 * 64];  // 16KB per buf
  __shared__ __align__(16) __bf16 Vs[3][64 * 128];  // 16KB per buf
  const int t = threadIdx.x, w = t >> 6, l = t & 63;
  const int lq = l & 31, hi = l >> 5;
  const int id = blockIdx.x;
  const int bh = (id & 7) + 8 * (id >> 5);  // same-head blocks share an XCD
  const int p = (id >> 3) & 3;
  const int member = (w >> 2) & 1;
  const int ridx = (w & 3) | ((w >> 3) << 2);  // 0..7
  const int qb = member ? 7 - p : p;
  const int q0w = qb * 256 + ridx * 32;
  const int qrow = q0w + lq;
  const size_t kbaseB = (size_t)bh * (2048 * 64 * 2);
  const size_t vbaseB = (size_t)bh * (64 * 2048 * 2);

  const int srow = t >> 3;                               // 0..127 (K rows)
  const int scolb = ((t & 7) * 16) ^ ((srow & 7) << 4);  // inverse swizzle
  const int vrow = t >> 4;                               // 0..63 (V^T rows)
  const int vcolb = ((t & 15) * 16) ^ ((vrow & 15) << 4);
  const char* kgp = (const char*)Kb + kbaseB + (size_t)srow * 128 + scolb;
  const char* vgp = (const char*)VTg + vbaseB + (size_t)vrow * 4096 + vcolb;
  char* kl = (char*)&Ks[0][0] + w * 1024;  // wave-uniform dest
  char* vl = (char*)&Vs[0][0] + w * 1024;

#define STAGE(bi, KT)                                                      \
  {                                                                        \
    GL16(kgp + (size_t)(KT) * 16384, kl + (bi) * 16384);                   \
    GL16(vgp + (size_t)(KT) * 256, vl + (bi) * 16384);                     \
  }

  const size_t qbase = (size_t)bh * (2048 * 64);
  bf16x8 qf[4];
#pragma unroll
  for (int ds = 0; ds < 4; ++ds)
    qf[ds] = *(const bf16x8*)&Q[qbase + (size_t)qrow * 64 + ds * 16 + hi * 8];

  f32x16 o0 = {}, o1 = {};
  float lsum = 0.0f;

  const int nkt = 2 * (7 - p) + 2;  // block-uniform (heavy member bound)
  STAGE(0, 0)
  STAGE(1, 1)  // nkt >= 2 always (p <= 3 -> nkt >= 10)
  asm volatile("s_waitcnt vmcnt(2)" ::: "memory");
  __builtin_amdgcn_s_barrier();
  __builtin_amdgcn_sched_barrier(0);
  for (int kt = 0; kt < nkt; ++kt) {
    const int X = kt % 3;
    if (kt + 2 < nkt) STAGE((kt + 2) % 3, kt + 2)
    const char* kc = (const char*)&Ks[X][0];
    const char* vc = (const char*)&Vs[X][0];

#pragma unroll
    for (int sub = 0; sub < 2; ++sub) {
      const int k0 = kt * 128 + sub * 64;
      if (k0 <= q0w + 31) {  // warp-uniform causal skip
        const char* kcs = kc + sub * 8192;
        f32x16 s0, s1;
        __builtin_amdgcn_s_setprio(1);
        qkt(kcs, qf, lq, hi, s0, s1);
        __builtin_amdgcn_s_setprio(0);
        if (k0 + 63 > q0w) {  // causal mask (edge tiles only)
#pragma unroll
          for (int r = 0; r < 16; ++r) {
            int kl_ = k0 + (r & 3) + 8 * (r >> 2) + 4 * hi;
            s0[r] = (kl_ > qrow) ? -1e30f : s0[r];
            s1[r] = (kl_ + 32 > qrow) ? -1e30f : s1[r];
          }
        }
        bf16x8 pa[4];
        smexp(s0, s1, lsum, pa, hi);
        __builtin_amdgcn_s_setprio(1);
        pv(vc, sub * 128, lq, hi, pa, o0, o1);
        __builtin_amdgcn_s_setprio(0);
      }
    }
    if (kt + 2 < nkt) {
      asm volatile("s_waitcnt vmcnt(2)" ::: "memory");  // kt+1's loads only
    } else if (kt + 1 < nkt) {
      asm volatile("s_waitcnt vmcnt(0)" ::: "memory");
    }
    __builtin_amdgcn_s_barrier();
    __builtin_amdgcn_sched_barrier(0);
  }

  // epilogue: O^T reg r -> d = dtile*32 + (r&3) + 8*(r>>2) + 4*hi, q = lane&31
  const int b = bh >> 4, h = bh & 15;
  float inv = 1.0f / lsum;
  __bf16* orow = O + ((size_t)(b * 2048 + qrow)) * 1024 + h * 64;
#pragma unroll
  for (int rq = 0; rq < 4; ++rq) {
    bf16x4 v0, v1;
#pragma unroll
    for (int e = 0; e < 4; ++e) {
      v0[e] = (__bf16)(o0[rq * 4 + e] * inv);
      v1[e] = (__bf16)(o1[rq * 4 + e] * inv);
    }
    *(bf16x4*)&orow[8 * rq + 4 * hi] = v0;
    *(bf16x4*)&orow[32 + 8 * rq + 4 * hi] = v1;
  }
}

// ---------------------------------------------------------------------------
extern "C" void kernel_launch(void* const* d_in, const int* in_sizes, int n_in,
                              void* d_out, int out_size, void* d_ws, size_t ws_size,
                              hipStream_t stream) {
  const float* x = (const float*)d_in[0];
  const float* wq = (const float*)d_in[1];
  const float* wk = (const float*)d_in[2];
  const float* wv = (const float*)d_in[3];
  const float* wo = (const float*)d_in[4];
  const int* tpos = (const int*)d_in[5];
  float* out = (float*)d_out;

  const size_t SZ_X = 8192u * 1024u * 2u;
  const size_t SZ_W = 1024u * 1024u * 2u;
  const size_t SZ_T = 2048u * 32u * 4u;
  const size_t NEED = SZ_X * 4 + SZ_W * 4 + SZ_T * 2;
  if (ws_size < NEED) return;

  char* p = (char*)d_ws;
  __bf16* xb  = (__bf16*)p; p += SZ_X;   // reused as attention output (AO)
  __bf16* wqb = (__bf16*)p; p += SZ_W;   // 4 weights contiguous (wq|wk|wv|wo)
  __bf16* wkb = (__bf16*)p; p += SZ_W;
  __bf16* wvb = (__bf16*)p; p += SZ_W;
  __bf16* wob = (__bf16*)p; p += SZ_W;
  __bf16* Qb  = (__bf16*)p; p += SZ_X;   // Q | K | V^T contiguous
  __bf16* Kbf = (__bf16*)p; p += SZ_X;
  __bf16* VTg = (__bf16*)p; p += SZ_X;
  float* ct = (float*)p; p += SZ_T;
  float* st = (float*)p; p += SZ_T;
  __bf16* AOb = xb;
  (void)wkb; (void)wvb;

  cvt_all<<<12544, 256, 0, stream>>>(x, wq, wk, wv, wo, xb, wqb, ct, st);

  // fused QKV: B = wq|wk|wv rows (contiguous), N=3072; grid 1536 = 6/CU
  gemm8<4><<<1536, 256, 0, stream>>>(xb, wqb, (void*)Qb, tpos, ct, st);

  attn_fwd<<<256, 1024, 0, stream>>>(Qb, Kbf, VTg, AOb);

  // out projection: N=1024; grid 512 = 2/CU
  gemm8<3><<<512, 256, 0, stream>>>(AOb, wob, (void*)out, tpos, ct, st);
}